// Round 1
// baseline (731.615 us; speedup 1.0000x reference)
//
#include <hip/hip_runtime.h>

// ParabolicPool2D: out[b,c,i,j] = max_{p,q in 3x3} f[b,c,2i+p,2j+q] + h[c,p,q]
// h[c,p,q] = -zc[p,q]*t[c], zc = [[1,.5,1],[.5,0,.5],[1,.5,1]]
// Group taps by additive constant: center (+0), 4 edges (-0.5t), 4 corners (-t).
// max is monotone under fp rounding, so group-max-then-add == per-tap-add-then-max bitwise.
//
// R1: 2 output rows x 2 output cols per thread.
//  - 5 float4 row-loads -> 4 outputs (middle input row shared in registers),
//    vs 6 float4 + 6 scalar loads for the same 4 outputs before.
//  - overlap-tail element (col c0+4) via __shfl_down(v.x,1) instead of scalar loads:
//    off the VMEM pipe, and removes all conditional/OOB-adjacent loads.
//  - all loads issued up front (row-pair-1 address clamped for the i0==126 wave) for MLP.
//  - nontemporal stores: out is write-only, keep L2 for input row reuse.

constexpr int Bn = 16, Cn = 128, Hn = 256, Wn = 256;
constexpr int OH = 127, OW = 127;

__device__ __forceinline__ float max4(float a, float b, float c, float d) {
    return fmaxf(fmaxf(a, b), fmaxf(c, d));
}

// One output row from input rows A(top), B(mid), C(bot); tA/tB/tC = col c0+4 tails.
__device__ __forceinline__ void compute_pair(const float4& A, const float4& B, const float4& C,
                                             float tA, float tB, float tC,
                                             float eAdd, float kAdd,
                                             float& o0, float& o1) {
    // output j0   uses input cols c0..c0+2 -> (x,y,z)
    o0 = fmaxf(B.y, fmaxf(max4(A.y, C.y, B.x, B.z) + eAdd,
                          max4(A.x, A.z, C.x, C.z) + kAdd));
    // output j0+1 uses input cols c0+2..c0+4 -> (z,w,tail)
    o1 = fmaxf(B.w, fmaxf(max4(A.w, C.w, B.z, tB) + eAdd,
                          max4(A.z, tA, C.z, tC) + kAdd));
}

__global__ __launch_bounds__(256) void pp2d_kernel(const float* __restrict__ f,
                                                   const float* __restrict__ t,
                                                   float* __restrict__ out) {
    const int bc = blockIdx.y;                         // 0 .. B*C-1
    const int c  = bc & (Cn - 1);
    const int i0 = (blockIdx.x * 4 + threadIdx.y) * 2; // first output row of pair: 0,2,..,126
    const int tx = threadIdx.x;                        // 0..63
    const int j0 = tx * 2;                             // first output col (<=126, always valid)
    const bool has2    = (j0 + 1) < OW;                // tx==63 -> single col
    const bool hasRow1 = (i0 + 1) < OH;                // i0==126 -> single row (wave-uniform)

    const float tc   = t[c];
    const float eAdd = -0.5f * tc;   // edge taps
    const float kAdd = -tc;          // corner taps

    const float* fb = f + ((size_t)bc * Hn + (size_t)(2 * i0)) * Wn;
    const int c0 = 4 * tx;           // c0+3 <= 255 always; tail c0+4 comes from lane tx+1

    // Row pair 0 reads input rows 2i0..2i0+2; pair 1 reads 2i0+2..2i0+4 (v2 shared).
    // Clamp pair-1 addresses into bounds for the i0==126 wave (values unused there).
    const size_t off3 = hasRow1 ? (size_t)(3 * Wn) : 0;
    const float4 v0 = *(const float4*)(fb + c0);
    const float4 v1 = *(const float4*)(fb + Wn + c0);
    const float4 v2 = *(const float4*)(fb + 2 * Wn + c0);
    const float4 v3 = *(const float4*)(fb + off3 + c0);
    const float4 v4 = *(const float4*)(fb + off3 + Wn + c0);

    // tail element (input col c0+4) = neighbor lane's v.x; lane 63 value unused (has2=false)
    const float t0 = __shfl_down(v0.x, 1);
    const float t1 = __shfl_down(v1.x, 1);
    const float t2 = __shfl_down(v2.x, 1);
    const float t3 = __shfl_down(v3.x, 1);
    const float t4 = __shfl_down(v4.x, 1);

    float* orow = out + ((size_t)bc * OH + i0) * OW;

    float o0, o1;
    compute_pair(v0, v1, v2, t0, t1, t2, eAdd, kAdd, o0, o1);
    __builtin_nontemporal_store(o0, orow + j0);
    if (has2) __builtin_nontemporal_store(o1, orow + j0 + 1);

    if (hasRow1) {
        float p0, p1;
        compute_pair(v2, v3, v4, t2, t3, t4, eAdd, kAdd, p0, p1);
        float* orow1 = orow + OW;
        __builtin_nontemporal_store(p0, orow1 + j0);
        if (has2) __builtin_nontemporal_store(p1, orow1 + j0 + 1);
    }
}

extern "C" void kernel_launch(void* const* d_in, const int* in_sizes, int n_in,
                              void* d_out, int out_size, void* d_ws, size_t ws_size,
                              hipStream_t stream) {
    const float* f = (const float*)d_in[0];
    const float* t = (const float*)d_in[1];
    float* out = (float*)d_out;

    dim3 block(64, 4, 1);                 // 4 waves; each wave = one output-row-pair strip
    dim3 grid(16, Bn * Cn, 1);            // 16*4 row-pairs = 64 pairs -> rows 0..126 exactly
    pp2d_kernel<<<grid, block, 0, stream>>>(f, t, out);
}

// Round 2
// 710.478 us; speedup vs baseline: 1.0297x; 1.0297x over previous
//
#include <hip/hip_runtime.h>

// ParabolicPool2D: out[b,c,i,j] = max_{p,q in 3x3} f[b,c,2i+p,2j+q] + h[c,p,q]
// h[c,p,q] = -zc[p,q]*t[c], zc = [[1,.5,1],[.5,0,.5],[1,.5,1]]
// Group taps by additive constant: center (+0), 4 edges (-0.5t), 4 corners (-t).
// max is monotone under fp rounding, so group-max-then-add == per-tap-add-then-max bitwise.
//
// R2: 2 output rows x 2 output cols per thread (keeps R1's 5 float4 / 4 outputs reuse),
//     but reverts R1's two regressions:
//  - plain stores (nontemporal partial-508B-row writes defeated L2 write merging)
//  - tail element (col c0+4) via guarded scalar load (L1 hit on the line lane tx+1
//    just fetched) instead of __shfl_down's DS-pipe vmcnt->lgkmcnt serialization.

constexpr int Bn = 16, Cn = 128, Hn = 256, Wn = 256;
constexpr int OH = 127, OW = 127;

__device__ __forceinline__ float max4(float a, float b, float c, float d) {
    return fmaxf(fmaxf(a, b), fmaxf(c, d));
}

// One output row-pair from input rows A(top), B(mid), C(bot); tA/tB/tC = col c0+4 tails.
__device__ __forceinline__ void compute_pair(const float4& A, const float4& B, const float4& C,
                                             float tA, float tB, float tC,
                                             float eAdd, float kAdd,
                                             float& o0, float& o1) {
    // output j0   uses input cols c0..c0+2 -> (x,y,z)
    o0 = fmaxf(B.y, fmaxf(max4(A.y, C.y, B.x, B.z) + eAdd,
                          max4(A.x, A.z, C.x, C.z) + kAdd));
    // output j0+1 uses input cols c0+2..c0+4 -> (z,w,tail)
    o1 = fmaxf(B.w, fmaxf(max4(A.w, C.w, B.z, tB) + eAdd,
                          max4(A.z, tA, C.z, tC) + kAdd));
}

__global__ __launch_bounds__(256) void pp2d_kernel(const float* __restrict__ f,
                                                   const float* __restrict__ t,
                                                   float* __restrict__ out) {
    const int bc = blockIdx.y;                         // 0 .. B*C-1
    const int c  = bc & (Cn - 1);
    const int i0 = (blockIdx.x * 4 + threadIdx.y) * 2; // first output row of pair: 0,2,..,126
    const int tx = threadIdx.x;                        // 0..63
    const int j0 = tx * 2;                             // first output col (<=126, always valid)
    const bool has2    = (j0 + 1) < OW;                // tx==63 -> single col
    const bool hasRow1 = (i0 + 1) < OH;                // i0==126 -> single row (wave-uniform)

    const float tc   = t[c];
    const float eAdd = -0.5f * tc;   // edge taps
    const float kAdd = -tc;          // corner taps

    const float* fb = f + ((size_t)bc * Hn + (size_t)(2 * i0)) * Wn;
    const int c0 = 4 * tx;           // c0+3 <= 255 always

    // Row pair 0 reads input rows 2i0..2i0+2; pair 1 reads 2i0+2..2i0+4 (v2 shared).
    // Clamp pair-1 addresses into bounds for the i0==126 wave (values unused there).
    const size_t off3 = hasRow1 ? (size_t)(3 * Wn) : 0;
    const float4 v0 = *(const float4*)(fb + c0);
    const float4 v1 = *(const float4*)(fb + Wn + c0);
    const float4 v2 = *(const float4*)(fb + 2 * Wn + c0);
    const float4 v3 = *(const float4*)(fb + off3 + c0);
    const float4 v4 = *(const float4*)(fb + off3 + Wn + c0);

    // tail element (input col c0+4): L1-hit scalar loads; OOB only when tx==63 (guarded)
    float t0 = 0.f, t1 = 0.f, t2 = 0.f, t3 = 0.f, t4 = 0.f;
    if (has2) {
        t0 = fb[c0 + 4];
        t1 = fb[Wn + c0 + 4];
        t2 = fb[2 * Wn + c0 + 4];
        t3 = fb[off3 + c0 + 4];
        t4 = fb[off3 + Wn + c0 + 4];
    }

    float* orow = out + ((size_t)bc * OH + i0) * OW;

    float o0, o1;
    compute_pair(v0, v1, v2, t0, t1, t2, eAdd, kAdd, o0, o1);
    orow[j0] = o0;
    if (has2) orow[j0 + 1] = o1;

    if (hasRow1) {
        float p0, p1;
        compute_pair(v2, v3, v4, t2, t3, t4, eAdd, kAdd, p0, p1);
        float* orow1 = orow + OW;
        orow1[j0] = p0;
        if (has2) orow1[j0 + 1] = p1;
    }
}

extern "C" void kernel_launch(void* const* d_in, const int* in_sizes, int n_in,
                              void* d_out, int out_size, void* d_ws, size_t ws_size,
                              hipStream_t stream) {
    const float* f = (const float*)d_in[0];
    const float* t = (const float*)d_in[1];
    float* out = (float*)d_out;

    dim3 block(64, 4, 1);                 // 4 waves; each wave = one output-row-pair strip
    dim3 grid(16, Bn * Cn, 1);            // 16*4 row-pairs = 64 pairs -> rows 0..126 exactly
    pp2d_kernel<<<grid, block, 0, stream>>>(f, t, out);
}